// Round 7
// baseline (407.975 us; speedup 1.0000x reference)
//
#include <hip/hip_runtime.h>

typedef unsigned short u16;
typedef unsigned int u32;
typedef __attribute__((ext_vector_type(8))) short bf16x8;   // 8 bf16 = 4 VGPRs
typedef __attribute__((ext_vector_type(4))) float f32x4;
typedef __attribute__((ext_vector_type(2))) unsigned int u32x2;

#define NBATCH 4
#define DDIM   128
#define NHEAD  8
#define PTOT   12544
#define CWID   112     // patch grid width
#define NTOK   49      // tokens per 7x7 window
#define PSTR   68      // p_lds row stride (u16 elems)

// LDS region offsets (u16 units)
#define OFF_XW 0                    // 49*128 = 6272
#define OFF_QS 6272                 // 49*128 = 6272   (reused as O^T [j][dh])
#define OFF_KS 12544                // 49*128 = 6272
#define OFF_VS 18816                // 128*64 = 8192
#define OFF_PL 27008                // 64*68  = 4352
#define OFF_PC 31360                // 169*8  = 1352  (bf16 pos bias)
#define LDS_TOT 32712               // 65424 bytes -> 2 blocks/CU; 8 waves/block -> 16 waves/CU

__device__ __forceinline__ int swz128(int row, int col) {
    return row * 128 + ((((col >> 3) ^ row) & 15) << 3) + (col & 7);
}
__device__ __forceinline__ int swz64(int row, int col) {
    return row * 64 + ((((col >> 3) ^ row) & 7) << 3) + (col & 7);
}
__device__ __forceinline__ float bf2f(u16 u) {
    union { u32 i; float f; } x; x.i = ((u32)u) << 16; return x.f;
}
__device__ __forceinline__ u16 f2bf(float f) {
    union { float f; u32 u; } v; v.f = f;
    return (u16)((v.u + 0x7fffu + ((v.u >> 16) & 1u)) >> 16);
}

// ---- prepass: weights fp32 -> bf16 into ws (Wq|Wk|Wv|Wo, 131072 u16 each) ----
__global__ void __launch_bounds__(256) cvt_ws(
    const float* __restrict__ Wq, const float* __restrict__ Wk,
    const float* __restrict__ Wv, const float* __restrict__ Wo,
    u16* __restrict__ ws)
{
    const float* src[4] = {Wq, Wk, Wv, Wo};
    for (int t = blockIdx.x * 256 + threadIdx.x; t < 4 * 131072; t += gridDim.x * 256)
        ws[t] = f2bf(src[t >> 17][t & 131071]);
}

// 512 threads = 8 waves. Wave roles: w8 = tid>>6; jg = w8&3 (query group),
// half = w8>>2 (dh half for PV). Occupancy: 2 blocks/CU (LDS) x 8 waves = 50%.
__global__ void __launch_bounds__(512, 4)
winattn(const float* __restrict__ xg, const u16* __restrict__ wsW,
        const float* __restrict__ bq, const float* __restrict__ bk,
        const float* __restrict__ bv, const float* __restrict__ bo,
        const float* __restrict__ posf, float* __restrict__ out)
{
    __shared__ u16 sm[LDS_TOT];
    u16* xw = sm + OFF_XW;   // x window  [t][d]   bf16
    u16* qs = sm + OFF_QS;   // q^T       [t][d]   / later O^T [j][dh]
    u16* ks = sm + OFF_KS;   // k^T       [t][d]
    u16* vs = sm + OFF_VS;   // v         [dh][i]
    u16* pl = sm + OFF_PL;   // P^T       [j][i], stride PSTR
    u16* pc = sm + OFF_PC;   // pos_code  [169][8] bf16

    const int tid  = threadIdx.x;
    const int w8   = tid >> 6;        // wave 0..7
    const int jg   = w8 & 3;          // j-group (16 queries)
    const int half = w8 >> 2;         // dh half for PV
    const int lane = tid & 63;
    const int quad = lane >> 4;
    const int lid  = lane & 15;
    const int bx   = blockIdx.x;
    const int n    = bx >> 8;
    const int win  = bx & 255;
    const int pbase = (win >> 4) * 7 * CWID + (win & 15) * 7;

    const bf16x8 zf = {0,0,0,0,0,0,0,0};
    const f32x4  z4 = {0.f,0.f,0.f,0.f};

    const u16* Wqw = wsW;
    const u16* Wkw = wsW + 131072;
    const u16* Wvw = wsW + 262144;
    const u16* Wow = wsW + 393216;

    // ---- stage pos_code + x window (fp32 inputs, bf16 LDS) ----
    for (int i = tid; i < 169 * NHEAD; i += 512) pc[i] = f2bf(posf[i]);
    const float* xn = xg + n * DDIM * PTOT;
    for (int idx = tid; idx < DDIM * NTOK; idx += 512) {
        int d = idx / NTOK;
        int t = idx - d * NTOK;
        int a = t / 7, b = t - a * 7;
        xw[swz128(t, d)] = f2bf(xn[d * PTOT + pbase + a * CWID + b]);
    }
    __syncthreads();

    // persistent accumulators: out^T rows (all j), dd tile w8 (16 chans)
    f32x4 outacc[4];
    #pragma unroll
    for (int mt = 0; mt < 4; ++mt) outacc[mt] = z4;

    const int j = 16 * jg + lid;      // this lane's query column (S/PV stages)

    for (int h = 0; h < NHEAD; ++h) {
        // ======== stage A: projections (8 waves: 1 dh-tile each) ========
        for (int sel = 0; sel < 2; ++sel) {
            const u16* W    = sel ? Wkw : Wqw;
            const float* bb = sel ? bk : bq;
            u16* dst        = sel ? ks : qs;
            const int nt = w8;
            const int drow = h * 128 + nt * 16 + lid;
            bf16x8 B[4];
            #pragma unroll
            for (int kt = 0; kt < 4; ++kt)
                B[kt] = *(const bf16x8*)(W + drow * 128 + kt * 32 + quad * 8);
            const float bias = bb[drow];
            #pragma unroll
            for (int mt = 0; mt < 4; ++mt) {
                f32x4 acc = z4;
                #pragma unroll
                for (int kt = 0; kt < 4; ++kt) {
                    bf16x8 A = zf;
                    if (mt * 16 + lid < NTOK)
                        A = *(const bf16x8*)(xw + swz128(mt * 16 + lid, kt * 32 + quad * 8));
                    acc = __builtin_amdgcn_mfma_f32_16x16x32_bf16(A, B[kt], acc, 0, 0, 0);
                }
                #pragma unroll
                for (int r = 0; r < 4; ++r) {
                    const int t = mt * 16 + quad * 4 + r;
                    if (t < NTOK)
                        dst[swz128(t, nt * 16 + lid)] = f2bf(acc[r] + bias);
                }
            }
        }
        // v : wave w8 owns m-tile w8 (dh rows), all token cols
        {
            const int mt = w8;
            const int drow = h * 128 + mt * 16 + lid;
            bf16x8 A[4];
            #pragma unroll
            for (int kt = 0; kt < 4; ++kt)
                A[kt] = *(const bf16x8*)(Wvw + drow * 128 + kt * 32 + quad * 8);
            float bias[4];
            #pragma unroll
            for (int r = 0; r < 4; ++r)
                bias[r] = bv[h * 128 + mt * 16 + quad * 4 + r];
            #pragma unroll
            for (int nt = 0; nt < 4; ++nt) {
                f32x4 acc = z4;
                #pragma unroll
                for (int kt = 0; kt < 4; ++kt) {
                    bf16x8 Bx = zf;
                    if (nt * 16 + lid < NTOK)
                        Bx = *(const bf16x8*)(xw + swz128(nt * 16 + lid, kt * 32 + quad * 8));
                    acc = __builtin_amdgcn_mfma_f32_16x16x32_bf16(A[kt], Bx, acc, 0, 0, 0);
                }
                #pragma unroll
                for (int r = 0; r < 4; ++r)
                    vs[swz64(mt * 16 + quad * 4 + r, nt * 16 + lid)] = f2bf(acc[r] + bias[r]);
            }
        }
        __syncthreads();

        // ======== stage B: S = k^T q + softmax (waves 0..3 only) ========
        if (half == 0) {
            bf16x8 Bq[4];
            #pragma unroll
            for (int kt = 0; kt < 4; ++kt) {
                Bq[kt] = zf;
                if (j < NTOK)
                    Bq[kt] = *(const bf16x8*)(qs + swz128(j, kt * 32 + quad * 8));
            }
            f32x4 S[4];
            #pragma unroll
            for (int mt = 0; mt < 4; ++mt) {
                S[mt] = z4;
                #pragma unroll
                for (int kt = 0; kt < 4; ++kt) {
                    bf16x8 A = *(const bf16x8*)(ks + swz128(mt * 16 + lid, kt * 32 + quad * 8));
                    S[mt] = __builtin_amdgcn_mfma_f32_16x16x32_bf16(A, Bq[kt], S[mt], 0, 0, 0);
                }
            }
            const int jc = j < NTOK ? j : NTOK - 1;
            const int aj = jc / 7, bj = jc - aj * 7;
            float sv[4][4];
            float mx = -3.0e38f;
            #pragma unroll
            for (int mt = 0; mt < 4; ++mt)
                #pragma unroll
                for (int r = 0; r < 4; ++r) {
                    const int ii = mt * 16 + quad * 4 + r;
                    float vvv;
                    if (ii < NTOK) {
                        const int ai = ii / 7, bi = ii - ai * 7;
                        const int rel = (ai - aj + 6) + 13 * (bi - bj + 6);
                        vvv = S[mt][r] * 0.08838834764831845f + bf2f(pc[rel * NHEAD + h]);
                    } else {
                        vvv = -3.0e38f;
                    }
                    sv[mt][r] = vvv;
                    mx = fmaxf(mx, vvv);
                }
            mx = fmaxf(mx, __shfl_xor(mx, 16));
            mx = fmaxf(mx, __shfl_xor(mx, 32));
            float ssum = 0.f;
            #pragma unroll
            for (int mt = 0; mt < 4; ++mt)
                #pragma unroll
                for (int r = 0; r < 4; ++r) {
                    const float e = __expf(sv[mt][r] - mx);
                    sv[mt][r] = e;
                    ssum += e;
                }
            ssum += __shfl_xor(ssum, 16);
            ssum += __shfl_xor(ssum, 32);
            const float inv = 1.0f / ssum;
            #pragma unroll
            for (int mt = 0; mt < 4; ++mt) {
                union { u16 s[4]; u32x2 u; } pk;
                #pragma unroll
                for (int r = 0; r < 4; ++r) pk.s[r] = f2bf(sv[mt][r] * inv);
                *(u32x2*)(pl + j * PSTR + mt * 16 + quad * 4) = pk.u;
            }
        }
        __syncthreads();   // P^T visibility + qs reads complete (O^T overlays qs)

        // ======== stage C: O^T = P^T x v^T (wave: j-group jg, dh half) ========
        {
            f32x4 O[4];
            #pragma unroll
            for (int nt = 0; nt < 4; ++nt) O[nt] = z4;
            #pragma unroll
            for (int kt = 0; kt < 2; ++kt) {
                union { bf16x8 v; u32 u[4]; } Af;
                #pragma unroll
                for (int q2 = 0; q2 < 4; ++q2)
                    Af.u[q2] = *(const u32*)(pl + j * PSTR + kt * 32 + quad * 8 + 2 * q2);
                #pragma unroll
                for (int nt = 0; nt < 4; ++nt) {
                    const int dcol = (4 * half + nt) * 16 + lid;
                    bf16x8 Bv = *(const bf16x8*)(vs + swz64(dcol, kt * 32 + quad * 8));
                    O[nt] = __builtin_amdgcn_mfma_f32_16x16x32_bf16(Af.v, Bv, O[nt], 0, 0, 0);
                }
            }
            #pragma unroll
            for (int nt = 0; nt < 4; ++nt)
                #pragma unroll
                for (int r = 0; r < 4; ++r) {
                    const int jr = 16 * jg + quad * 4 + r;
                    if (jr < NTOK)
                        qs[swz128(jr, (4 * half + nt) * 16 + lid)] = f2bf(O[nt][r]);
                }
        }
        __syncthreads();

        // ======== stage D: out^T += O^T x Wo_h^T (wave w8: dd tile w8) ========
        {
            const int dro = w8 * 16 + lid;
            bf16x8 B[4];
            #pragma unroll
            for (int kt = 0; kt < 4; ++kt)
                B[kt] = *(const bf16x8*)(Wow + dro * 1024 + h * 128 + kt * 32 + quad * 8);
            #pragma unroll
            for (int mt = 0; mt < 4; ++mt) {
                #pragma unroll
                for (int kt = 0; kt < 4; ++kt) {
                    bf16x8 A = *(const bf16x8*)(qs + swz128(mt * 16 + lid, kt * 32 + quad * 8));
                    outacc[mt] = __builtin_amdgcn_mfma_f32_16x16x32_bf16(A, B[kt], outacc[mt], 0, 0, 0);
                }
            }
        }
        __syncthreads();   // before next head overwrites qs/ks/vs
    }

    // ======== epilogue: out[n][dd][p] = acc + bo[dd]  (fp32 output) ========
    float* outp = out + n * DDIM * PTOT;
    {
        const int dd = w8 * 16 + lid;
        const float bov = bo[dd];
        #pragma unroll
        for (int mt = 0; mt < 4; ++mt)
            #pragma unroll
            for (int r = 0; r < 4; ++r) {
                const int jj = mt * 16 + quad * 4 + r;
                if (jj < NTOK) {
                    const int a = jj / 7, b = jj - a * 7;
                    outp[dd * PTOT + pbase + a * CWID + b] = outacc[mt][r] + bov;
                }
            }
    }
}

extern "C" void kernel_launch(void* const* d_in, const int* in_sizes, int n_in,
                              void* d_out, int out_size, void* d_ws, size_t ws_size,
                              hipStream_t stream) {
    (void)in_sizes; (void)n_in; (void)ws_size; (void)out_size;
    cvt_ws<<<256, 256, 0, stream>>>((const float*)d_in[1], (const float*)d_in[3],
                                    (const float*)d_in[5], (const float*)d_in[7],
                                    (u16*)d_ws);
    winattn<<<NBATCH * 256, 512, 0, stream>>>(
        (const float*)d_in[0], (const u16*)d_ws,
        (const float*)d_in[2], (const float*)d_in[4],
        (const float*)d_in[6], (const float*)d_in[8],
        (const float*)d_in[9], (float*)d_out);
}

// Round 8
// 307.985 us; speedup vs baseline: 1.3247x; 1.3247x over previous
//
#include <hip/hip_runtime.h>

typedef unsigned short u16;
typedef unsigned int u32;
typedef __attribute__((ext_vector_type(8))) short bf16x8;   // 8 bf16 = 4 VGPRs
typedef __attribute__((ext_vector_type(4))) float f32x4;
typedef __attribute__((ext_vector_type(2))) unsigned int u32x2;

#define NBATCH 4
#define DDIM   128
#define NHEAD  8
#define PTOT   12544
#define CWID   112     // patch grid width
#define NTOK   49      // tokens per 7x7 window
#define PSTR   68      // p_lds row stride (u16 elems)

// LDS region offsets (u16 units). P^T overlays ks (k dead after S-MFMA reads).
#define OFF_XW 0                    // 49*128 = 6272
#define OFF_QS 6272                 // 49*128 = 6272   (reused as O^T [j][dh])
#define OFF_KS 12544                // 49*128 = 6272   (pl overlays: 49*68=3332 u16)
#define OFF_VS 18816                // 128*64 = 8192
#define LDS_TOT 27008               // 54016 B -> alloc 54272 -> 3 blocks/CU (12 waves)

__device__ __forceinline__ int swz128(int row, int col) {
    return row * 128 + ((((col >> 3) ^ row) & 15) << 3) + (col & 7);
}
__device__ __forceinline__ int swz64(int row, int col) {
    return row * 64 + ((((col >> 3) ^ row) & 7) << 3) + (col & 7);
}
__device__ __forceinline__ float bf2f(u16 u) {
    union { u32 i; float f; } x; x.i = ((u32)u) << 16; return x.f;
}
__device__ __forceinline__ u16 f2bf(float f) {
    union { float f; u32 u; } v; v.f = f;
    return (u16)((v.u + 0x7fffu + ((v.u >> 16) & 1u)) >> 16);
}

// ---- prepass: weights fp32 -> bf16 into ws (Wq|Wk|Wv|Wo, 131072 u16 each) ----
__global__ void __launch_bounds__(256) cvt_ws(
    const float* __restrict__ Wq, const float* __restrict__ Wk,
    const float* __restrict__ Wv, const float* __restrict__ Wo,
    u16* __restrict__ ws)
{
    const float* src[4] = {Wq, Wk, Wv, Wo};
    for (int t = blockIdx.x * 256 + threadIdx.x; t < 4 * 131072; t += gridDim.x * 256)
        ws[t] = f2bf(src[t >> 17][t & 131071]);
}

// 256 threads = 4 waves; wave w owns query group j in [16w,16w+16).
// LDS 54KB -> 3 blocks/CU: independent blocks overlap pipeline stages.
__global__ void __launch_bounds__(256, 2)
winattn(const float* __restrict__ xg, const u16* __restrict__ wsW,
        const float* __restrict__ bq, const float* __restrict__ bk,
        const float* __restrict__ bv, const float* __restrict__ bo,
        const float* __restrict__ posf, float* __restrict__ out)
{
    __shared__ u16 sm[LDS_TOT];
    u16* xw = sm + OFF_XW;   // x window  [t][d]   bf16
    u16* qs = sm + OFF_QS;   // q^T       [t][d]   / later O^T [j][dh]
    u16* ks = sm + OFF_KS;   // k^T       [t][d]
    u16* vs = sm + OFF_VS;   // v         [dh][i]
    u16* pl = sm + OFF_KS;   // P^T [j][i] stride PSTR — overlays ks after S reads

    const int tid  = threadIdx.x;
    const int w    = tid >> 6;        // wave id 0..3
    const int lane = tid & 63;
    const int quad = lane >> 4;
    const int lid  = lane & 15;
    const int bx   = blockIdx.x;
    const int n    = bx >> 8;
    const int win  = bx & 255;
    const int pbase = (win >> 4) * 7 * CWID + (win & 15) * 7;

    const bf16x8 zf = {0,0,0,0,0,0,0,0};
    const f32x4  z4 = {0.f,0.f,0.f,0.f};

    const u16* Wqw = wsW;
    const u16* Wkw = wsW + 131072;
    const u16* Wvw = wsW + 262144;
    const u16* Wow = wsW + 393216;

    // ---- stage x window (fp32 input -> bf16 LDS) ----
    const float* xn = xg + n * DDIM * PTOT;
    for (int idx = tid; idx < DDIM * NTOK; idx += 256) {
        int d = idx / NTOK;
        int t = idx - d * NTOK;
        int a = t / 7, b = t - a * 7;
        xw[swz128(t, d)] = f2bf(xn[d * PTOT + pbase + a * CWID + b]);
    }
    __syncthreads();

    // persistent accumulators: out^T[j rows][dd in [32w,32w+32)]
    f32x4 outacc[4][2];
    #pragma unroll
    for (int mt = 0; mt < 4; ++mt)
        #pragma unroll
        for (int ntl = 0; ntl < 2; ++ntl) outacc[mt][ntl] = z4;

    const int j = 16 * w + lid;       // this lane's query column
    const int jc = j < NTOK ? j : NTOK - 1;

    for (int h = 0; h < NHEAD; ++h) {
        // ======== stage A: projections ========
        for (int sel = 0; sel < 2; ++sel) {
            const u16* W    = sel ? Wkw : Wqw;
            const float* bb = sel ? bk : bq;
            u16* dst        = sel ? ks : qs;
            #pragma unroll
            for (int ntl = 0; ntl < 2; ++ntl) {
                const int nt = 2 * w + ntl;
                const int drow = h * 128 + nt * 16 + lid;
                bf16x8 B[4];
                #pragma unroll
                for (int kt = 0; kt < 4; ++kt)
                    B[kt] = *(const bf16x8*)(W + drow * 128 + kt * 32 + quad * 8);
                const float bias = bb[drow];
                #pragma unroll
                for (int mt = 0; mt < 4; ++mt) {
                    f32x4 acc = z4;
                    #pragma unroll
                    for (int kt = 0; kt < 4; ++kt) {
                        bf16x8 A = zf;
                        if (mt * 16 + lid < NTOK)
                            A = *(const bf16x8*)(xw + swz128(mt * 16 + lid, kt * 32 + quad * 8));
                        acc = __builtin_amdgcn_mfma_f32_16x16x32_bf16(A, B[kt], acc, 0, 0, 0);
                    }
                    #pragma unroll
                    for (int r = 0; r < 4; ++r) {
                        const int t = mt * 16 + quad * 4 + r;
                        if (t < NTOK)
                            dst[swz128(t, nt * 16 + lid)] = f2bf(acc[r] + bias);
                    }
                }
            }
        }
        // v : wave handles m-tiles {2w,2w+1} (dh rows), all token cols
        #pragma unroll
        for (int mtl = 0; mtl < 2; ++mtl) {
            const int mt = 2 * w + mtl;
            const int drow = h * 128 + mt * 16 + lid;
            bf16x8 A[4];
            #pragma unroll
            for (int kt = 0; kt < 4; ++kt)
                A[kt] = *(const bf16x8*)(Wvw + drow * 128 + kt * 32 + quad * 8);
            float bias[4];
            #pragma unroll
            for (int r = 0; r < 4; ++r)
                bias[r] = bv[h * 128 + mt * 16 + quad * 4 + r];
            #pragma unroll
            for (int nt = 0; nt < 4; ++nt) {
                f32x4 acc = z4;
                #pragma unroll
                for (int kt = 0; kt < 4; ++kt) {
                    bf16x8 Bx = zf;
                    if (nt * 16 + lid < NTOK)
                        Bx = *(const bf16x8*)(xw + swz128(nt * 16 + lid, kt * 32 + quad * 8));
                    acc = __builtin_amdgcn_mfma_f32_16x16x32_bf16(A[kt], Bx, acc, 0, 0, 0);
                }
                #pragma unroll
                for (int r = 0; r < 4; ++r)
                    vs[swz64(mt * 16 + quad * 4 + r, nt * 16 + lid)] = f2bf(acc[r] + bias[r]);
            }
        }
        __syncthreads();

        // ======== stage B: S = k^T q, softmax ========
        bf16x8 Bq[4];
        #pragma unroll
        for (int kt = 0; kt < 4; ++kt) {
            Bq[kt] = zf;
            if (j < NTOK)
                Bq[kt] = *(const bf16x8*)(qs + swz128(j, kt * 32 + quad * 8));
        }
        f32x4 S[4];
        #pragma unroll
        for (int mt = 0; mt < 4; ++mt) {
            S[mt] = z4;
            #pragma unroll
            for (int kt = 0; kt < 4; ++kt) {
                bf16x8 A = *(const bf16x8*)(ks + swz128(mt * 16 + lid, kt * 32 + quad * 8));
                S[mt] = __builtin_amdgcn_mfma_f32_16x16x32_bf16(A, Bq[kt], S[mt], 0, 0, 0);
            }
        }
        __syncthreads();   // all ks reads done -> pl may overlay ks region

        const int aj = jc / 7, bj = jc - aj * 7;
        float sv[4][4];
        float mx = -3.0e38f;
        #pragma unroll
        for (int mt = 0; mt < 4; ++mt)
            #pragma unroll
            for (int r = 0; r < 4; ++r) {
                const int ii = mt * 16 + quad * 4 + r;
                float vvv;
                if (ii < NTOK) {
                    const int ai = ii / 7, bi = ii - ai * 7;
                    const int rel = (ai - aj + 6) + 13 * (bi - bj + 6);
                    vvv = S[mt][r] * 0.08838834764831845f + posf[rel * NHEAD + h];
                } else {
                    vvv = -3.0e38f;
                }
                sv[mt][r] = vvv;
                mx = fmaxf(mx, vvv);
            }
        mx = fmaxf(mx, __shfl_xor(mx, 16));
        mx = fmaxf(mx, __shfl_xor(mx, 32));
        float ssum = 0.f;
        #pragma unroll
        for (int mt = 0; mt < 4; ++mt)
            #pragma unroll
            for (int r = 0; r < 4; ++r) {
                const float e = __expf(sv[mt][r] - mx);
                sv[mt][r] = e;
                ssum += e;
            }
        ssum += __shfl_xor(ssum, 16);
        ssum += __shfl_xor(ssum, 32);
        const float inv = 1.0f / ssum;
        if (j < NTOK) {   // rows 49..63 dropped (reads clamp to row 48)
            #pragma unroll
            for (int mt = 0; mt < 4; ++mt) {
                union { u16 s[4]; u32x2 u; } pk;
                #pragma unroll
                for (int r = 0; r < 4; ++r) pk.s[r] = f2bf(sv[mt][r] * inv);
                *(u32x2*)(pl + j * PSTR + mt * 16 + quad * 4) = pk.u;
            }
        }
        __syncthreads();   // P^T cross-lane visibility

        // ======== stage C: O^T = P^T x v^T (rows j-group, cols dh 0..127) ========
        f32x4 O[8];
        #pragma unroll
        for (int nt = 0; nt < 8; ++nt) O[nt] = z4;
        #pragma unroll
        for (int kt = 0; kt < 2; ++kt) {
            union { bf16x8 v; u32 u[4]; } Af;
            #pragma unroll
            for (int q2 = 0; q2 < 4; ++q2)
                Af.u[q2] = *(const u32*)(pl + jc * PSTR + kt * 32 + quad * 8 + 2 * q2);
            #pragma unroll
            for (int nt = 0; nt < 8; ++nt) {
                bf16x8 Bv = *(const bf16x8*)(vs + swz64(nt * 16 + lid, kt * 32 + quad * 8));
                O[nt] = __builtin_amdgcn_mfma_f32_16x16x32_bf16(Af.v, Bv, O[nt], 0, 0, 0);
            }
        }
        #pragma unroll
        for (int nt = 0; nt < 8; ++nt)
            #pragma unroll
            for (int r = 0; r < 4; ++r) {
                const int jr = 16 * w + quad * 4 + r;
                if (jr < NTOK)
                    qs[swz128(jr, nt * 16 + lid)] = f2bf(O[nt][r]);
            }
        __syncthreads();

        // ======== stage D: out^T += O^T x Wo_h^T ========
        #pragma unroll
        for (int ntl = 0; ntl < 2; ++ntl) {
            const int dro = (2 * w + ntl) * 16 + lid;
            bf16x8 B[4];
            #pragma unroll
            for (int kt = 0; kt < 4; ++kt)
                B[kt] = *(const bf16x8*)(Wow + dro * 1024 + h * 128 + kt * 32 + quad * 8);
            #pragma unroll
            for (int mt = 0; mt < 4; ++mt) {
                #pragma unroll
                for (int kt = 0; kt < 4; ++kt) {
                    bf16x8 A = *(const bf16x8*)(qs + swz128(mt * 16 + lid, kt * 32 + quad * 8));
                    outacc[mt][ntl] = __builtin_amdgcn_mfma_f32_16x16x32_bf16(A, B[kt], outacc[mt][ntl], 0, 0, 0);
                }
            }
        }
        __syncthreads();   // before next head overwrites qs/ks/vs
    }

    // ======== epilogue: out[n][dd][p] = acc + bo[dd]  (fp32 output) ========
    float* outp = out + n * DDIM * PTOT;
    #pragma unroll
    for (int ntl = 0; ntl < 2; ++ntl) {
        const int dd = (2 * w + ntl) * 16 + lid;
        const float bov = bo[dd];
        #pragma unroll
        for (int mt = 0; mt < 4; ++mt)
            #pragma unroll
            for (int r = 0; r < 4; ++r) {
                const int jj = mt * 16 + quad * 4 + r;
                if (jj < NTOK) {
                    const int a = jj / 7, b = jj - a * 7;
                    outp[dd * PTOT + pbase + a * CWID + b] = outacc[mt][ntl][r] + bov;
                }
            }
    }
}

extern "C" void kernel_launch(void* const* d_in, const int* in_sizes, int n_in,
                              void* d_out, int out_size, void* d_ws, size_t ws_size,
                              hipStream_t stream) {
    (void)in_sizes; (void)n_in; (void)ws_size; (void)out_size;
    cvt_ws<<<256, 256, 0, stream>>>((const float*)d_in[1], (const float*)d_in[3],
                                    (const float*)d_in[5], (const float*)d_in[7],
                                    (u16*)d_ws);
    winattn<<<NBATCH * 256, 256, 0, stream>>>(
        (const float*)d_in[0], (const u16*)d_ws,
        (const float*)d_in[2], (const float*)d_in[4],
        (const float*)d_in[6], (const float*)d_in[8],
        (const float*)d_in[9], (float*)d_out);
}

// Round 9
// 281.815 us; speedup vs baseline: 1.4477x; 1.0929x over previous
//
#include <hip/hip_runtime.h>

typedef unsigned short u16;
typedef unsigned int u32;
typedef __attribute__((ext_vector_type(8))) short bf16x8;   // 8 bf16 = 4 VGPRs
typedef __attribute__((ext_vector_type(4))) float f32x4;
typedef __attribute__((ext_vector_type(2))) unsigned int u32x2;

#define NBATCH 4
#define DDIM   128
#define NHEAD  8
#define PTOT   12544
#define CWID   112     // patch grid width
#define NTOK   49      // tokens per 7x7 window
#define PSTR   68      // p_lds row stride (u16 elems)

// LDS region offsets (u16 units)
#define OFF_XW 0                    // 49*128 = 6272  x window [t][d]
#define OFF_QS 6272                 // 49*128 = 6272  q^T [t][d]
#define OFF_KS 12544                // 49*128 = 6272  k^T [t][d]
#define OFF_US 18816                // 128*64 = 8192  U^T [dd][i]  (U = x*Wc^T + bcv)
#define OFF_PL 27008                // 49*68  = 3332  P^T [j][i]
#define OFF_PC 30340                // 169*8  = 1352  pos bias bf16
#define LDS_TOT 31692               // 63384 B -> 2 blocks/CU (8 waves)

// ws layout (u16 units): Wq16 | Wk16 | Wc16 (8 heads x 128x128) | bcv fp32
#define WS_WK  131072
#define WS_WC  262144
#define WS_BCV 393216               // float* at this u16 offset, 1024 floats

__device__ __forceinline__ int swz128(int row, int col) {
    return row * 128 + ((((col >> 3) ^ row) & 15) << 3) + (col & 7);
}
__device__ __forceinline__ int swz64(int row, int col) {
    return row * 64 + ((((col >> 3) ^ row) & 7) << 3) + (col & 7);
}
__device__ __forceinline__ float bf2f(u16 u) {
    union { u32 i; float f; } x; x.i = ((u32)u) << 16; return x.f;
}
__device__ __forceinline__ u16 f2bf(float f) {
    union { float f; u32 u; } v; v.f = f;
    return (u16)((v.u + 0x7fffu + ((v.u >> 16) & 1u)) >> 16);
}

// ---- prepass 1: Wq,Wk fp32 -> bf16 ----
__global__ void __launch_bounds__(256) cvt_ws(
    const float* __restrict__ Wq, const float* __restrict__ Wk, u16* __restrict__ ws)
{
    for (int t = blockIdx.x * 256 + threadIdx.x; t < 262144; t += gridDim.x * 256)
        ws[t] = f2bf(t < 131072 ? Wq[t] : Wk[t - 131072]);
}

// ---- prepass 2: Wc_h = Wo_h * Wv_h (fp32 math -> bf16), bcv_h = Wo_h * bv_h ----
__global__ void __launch_bounds__(256) wc_build(
    const float* __restrict__ Wv, const float* __restrict__ Wo,
    const float* __restrict__ bv, u16* __restrict__ ws)
{
    u16* wc = ws + WS_WC;
    float* bcv = (float*)(ws + WS_BCV);
    const int h = blockIdx.x >> 5;       // 8 heads x 32 chunks
    const int chunk = blockIdx.x & 31;
    const int e0 = chunk * 512;
    for (int e = e0 + threadIdx.x; e < e0 + 512; e += 256) {
        const int dd = e >> 7, d = e & 127;
        float s = 0.f;
        #pragma unroll 4
        for (int dh = 0; dh < 128; ++dh)
            s += Wo[dd * 1024 + h * 128 + dh] * Wv[(h * 128 + dh) * 128 + d];
        wc[h * 16384 + dd * 128 + d] = f2bf(s);
    }
    if (chunk == 0 && threadIdx.x < 128) {
        const int dd = threadIdx.x;
        float s = 0.f;
        for (int dh = 0; dh < 128; ++dh)
            s += Wo[dd * 1024 + h * 128 + dh] * bv[h * 128 + dh];
        bcv[h * 128 + dd] = s;
    }
}

// 256 threads = 4 waves; wave w owns query group j in [16w,16w+16).
// Per head: [A: q,k,U proj] sync [B: S + softmax + P write] fence [C': P^T U^T -> acc] sync
__global__ void __launch_bounds__(256, 2)
winattn(const float* __restrict__ xg, const u16* __restrict__ ws,
        const float* __restrict__ bq, const float* __restrict__ bk,
        const float* __restrict__ bo, const float* __restrict__ posf,
        float* __restrict__ out)
{
    __shared__ u16 sm[LDS_TOT];
    u16* xw = sm + OFF_XW;
    u16* qs = sm + OFF_QS;
    u16* ks = sm + OFF_KS;
    u16* us = sm + OFF_US;   // U^T [dd][i], stride 64 swizzled
    u16* pl = sm + OFF_PL;   // P^T [j][i], stride PSTR, wave-private rows
    u16* pc = sm + OFF_PC;   // pos bias [169][8] bf16

    const int tid  = threadIdx.x;
    const int w    = tid >> 6;
    const int lane = tid & 63;
    const int quad = lane >> 4;
    const int lid  = lane & 15;
    const int bx   = blockIdx.x;
    const int n    = bx >> 8;
    const int win  = bx & 255;
    const int pbase = (win >> 4) * 7 * CWID + (win & 15) * 7;

    const bf16x8 zf = {0,0,0,0,0,0,0,0};
    const f32x4  z4 = {0.f,0.f,0.f,0.f};

    const u16* Wqw = ws;
    const u16* Wkw = ws + WS_WK;
    const u16* Wcw = ws + WS_WC;
    const float* bcv = (const float*)(ws + WS_BCV);

    // ---- stage pos table + x window ----
    for (int i = tid; i < 169 * NHEAD; i += 256) pc[i] = f2bf(posf[i]);
    const float* xn = xg + n * DDIM * PTOT;
    for (int idx = tid; idx < DDIM * NTOK; idx += 256) {
        int d = idx / NTOK;
        int t = idx - d * NTOK;
        int a = t / 7, b = t - a * 7;
        xw[swz128(t, d)] = f2bf(xn[d * PTOT + pbase + a * CWID + b]);
    }
    __syncthreads();

    // persistent accumulators: out^T[j in wave's group][all 128 dd], C-layout
    f32x4 outacc[8];
    #pragma unroll
    for (int nt = 0; nt < 8; ++nt) outacc[nt] = z4;

    const int j = 16 * w + lid;
    const int jc = j < NTOK ? j : NTOK - 1;

    for (int h = 0; h < NHEAD; ++h) {
        // ======== stage A: q,k projections + U = x*Wc^T + bcv ========
        for (int sel = 0; sel < 2; ++sel) {
            const u16* W    = sel ? Wkw : Wqw;
            const float* bb = sel ? bk : bq;
            u16* dst        = sel ? ks : qs;
            #pragma unroll
            for (int ntl = 0; ntl < 2; ++ntl) {
                const int nt = 2 * w + ntl;
                const int drow = h * 128 + nt * 16 + lid;
                bf16x8 B[4];
                #pragma unroll
                for (int kt = 0; kt < 4; ++kt)
                    B[kt] = *(const bf16x8*)(W + drow * 128 + kt * 32 + quad * 8);
                const float bias = bb[drow];
                #pragma unroll
                for (int mt = 0; mt < 4; ++mt) {
                    f32x4 acc = z4;
                    #pragma unroll
                    for (int kt = 0; kt < 4; ++kt) {
                        bf16x8 A = zf;
                        if (mt * 16 + lid < NTOK)
                            A = *(const bf16x8*)(xw + swz128(mt * 16 + lid, kt * 32 + quad * 8));
                        acc = __builtin_amdgcn_mfma_f32_16x16x32_bf16(A, B[kt], acc, 0, 0, 0);
                    }
                    #pragma unroll
                    for (int r = 0; r < 4; ++r) {
                        const int t = mt * 16 + quad * 4 + r;
                        if (t < NTOK)
                            dst[swz128(t, nt * 16 + lid)] = f2bf(acc[r] + bias);
                    }
                }
            }
        }
        // U^T[dd][i] — wave handles dd-tiles {2w,2w+1}, all token cols
        #pragma unroll
        for (int mtl = 0; mtl < 2; ++mtl) {
            const int mt = 2 * w + mtl;
            bf16x8 A[4];
            #pragma unroll
            for (int kt = 0; kt < 4; ++kt)
                A[kt] = *(const bf16x8*)(Wcw + h * 16384 + (mt * 16 + lid) * 128 + kt * 32 + quad * 8);
            float bias[4];
            #pragma unroll
            for (int r = 0; r < 4; ++r)
                bias[r] = bcv[h * 128 + mt * 16 + quad * 4 + r];
            #pragma unroll
            for (int nt = 0; nt < 4; ++nt) {
                f32x4 acc = z4;
                #pragma unroll
                for (int kt = 0; kt < 4; ++kt) {
                    bf16x8 Bx = zf;
                    if (nt * 16 + lid < NTOK)
                        Bx = *(const bf16x8*)(xw + swz128(nt * 16 + lid, kt * 32 + quad * 8));
                    acc = __builtin_amdgcn_mfma_f32_16x16x32_bf16(A[kt], Bx, acc, 0, 0, 0);
                }
                #pragma unroll
                for (int r = 0; r < 4; ++r)
                    us[swz64(mt * 16 + quad * 4 + r, nt * 16 + lid)] = f2bf(acc[r] + bias[r]);
            }
        }
        __syncthreads();

        // ======== stage B: S = k^T q, softmax, P write (wave-local) ========
        bf16x8 Bq[4];
        #pragma unroll
        for (int kt = 0; kt < 4; ++kt) {
            Bq[kt] = zf;
            if (j < NTOK)
                Bq[kt] = *(const bf16x8*)(qs + swz128(j, kt * 32 + quad * 8));
        }
        f32x4 S[4];
        #pragma unroll
        for (int mt = 0; mt < 4; ++mt) {
            S[mt] = z4;
            #pragma unroll
            for (int kt = 0; kt < 4; ++kt) {
                bf16x8 A = *(const bf16x8*)(ks + swz128(mt * 16 + lid, kt * 32 + quad * 8));
                S[mt] = __builtin_amdgcn_mfma_f32_16x16x32_bf16(A, Bq[kt], S[mt], 0, 0, 0);
            }
        }
        const int aj = jc / 7, bj = jc - aj * 7;
        float sv[4][4];
        float mx = -3.0e38f;
        #pragma unroll
        for (int mt = 0; mt < 4; ++mt)
            #pragma unroll
            for (int r = 0; r < 4; ++r) {
                const int ii = mt * 16 + quad * 4 + r;
                float vvv;
                if (ii < NTOK) {
                    const int ai = ii / 7, bi = ii - ai * 7;
                    const int rel = (ai - aj + 6) + 13 * (bi - bj + 6);
                    vvv = S[mt][r] * 0.08838834764831845f + bf2f(pc[rel * NHEAD + h]);
                } else {
                    vvv = -3.0e38f;
                }
                sv[mt][r] = vvv;
                mx = fmaxf(mx, vvv);
            }
        mx = fmaxf(mx, __shfl_xor(mx, 16));
        mx = fmaxf(mx, __shfl_xor(mx, 32));
        float ssum = 0.f;
        #pragma unroll
        for (int mt = 0; mt < 4; ++mt)
            #pragma unroll
            for (int r = 0; r < 4; ++r) {
                const float e = __expf(sv[mt][r] - mx);
                sv[mt][r] = e;
                ssum += e;
            }
        ssum += __shfl_xor(ssum, 16);
        ssum += __shfl_xor(ssum, 32);
        const float inv = 1.0f / ssum;
        if (j < NTOK) {
            #pragma unroll
            for (int mt = 0; mt < 4; ++mt) {
                union { u16 s[4]; u32x2 u; } pk;
                #pragma unroll
                for (int r = 0; r < 4; ++r) pk.s[r] = f2bf(sv[mt][r] * inv);
                *(u32x2*)(pl + j * PSTR + mt * 16 + quad * 4) = pk.u;
            }
        }
        // P rows are wave-private: LDS drain + compiler fence is enough (no s_barrier)
        __threadfence_block();

        // ======== stage C': outacc += P^T x (U^T)^T  (j-group x all dd) ========
        #pragma unroll
        for (int kt = 0; kt < 2; ++kt) {
            union { bf16x8 v; u32 u[4]; } Af;
            #pragma unroll
            for (int q2 = 0; q2 < 4; ++q2)
                Af.u[q2] = *(const u32*)(pl + jc * PSTR + kt * 32 + quad * 8 + 2 * q2);
            #pragma unroll
            for (int nt = 0; nt < 8; ++nt) {
                bf16x8 Bu = *(const bf16x8*)(us + swz64(nt * 16 + lid, kt * 32 + quad * 8));
                outacc[nt] = __builtin_amdgcn_mfma_f32_16x16x32_bf16(Af.v, Bu, outacc[nt], 0, 0, 0);
            }
        }
        __syncthreads();   // before next head overwrites qs/ks/us
    }

    // ======== epilogue: out[n][dd][p(j)] = acc + bo[dd]  (fp32 output) ========
    float* outp = out + n * DDIM * PTOT;
    #pragma unroll
    for (int nt = 0; nt < 8; ++nt) {
        const int dd = nt * 16 + lid;
        const float bov = bo[dd];
        #pragma unroll
        for (int r = 0; r < 4; ++r) {
            const int jj = 16 * w + quad * 4 + r;
            if (jj < NTOK) {
                const int a = jj / 7, b = jj - a * 7;
                outp[dd * PTOT + pbase + a * CWID + b] = outacc[nt][r] + bov;
            }
        }
    }
}

extern "C" void kernel_launch(void* const* d_in, const int* in_sizes, int n_in,
                              void* d_out, int out_size, void* d_ws, size_t ws_size,
                              hipStream_t stream) {
    (void)in_sizes; (void)n_in; (void)ws_size; (void)out_size;
    cvt_ws<<<256, 256, 0, stream>>>((const float*)d_in[1], (const float*)d_in[3], (u16*)d_ws);
    wc_build<<<256, 256, 0, stream>>>((const float*)d_in[5], (const float*)d_in[7],
                                      (const float*)d_in[6], (u16*)d_ws);
    winattn<<<NBATCH * 256, 256, 0, stream>>>(
        (const float*)d_in[0], (const u16*)d_ws,
        (const float*)d_in[2], (const float*)d_in[4],
        (const float*)d_in[8], (const float*)d_in[9], (float*)d_out);
}